// Round 9
// baseline (67.194 us; speedup 1.0000x reference)
//
#include <hip/hip_runtime.h>

__device__ __forceinline__ float frcp(float x) { return __builtin_amdgcn_rcpf(x); }

template <int K>
__device__ __forceinline__ float rotr(float x) {
  // row_ror:K -> lane i receives lane (i-K)&15 within its 16-lane row
  return __int_as_float(
      __builtin_amdgcn_mov_dpp(__float_as_int(x), 0x120 + K, 0xf, 0xf, true));
}

// ---------------- Kernel A: level-1, register-resident recurrences ----------------
__global__ __launch_bounds__(256) void l1_kernel(
    const float* __restrict__ inp, const float* __restrict__ W1,
    const float* __restrict__ U1, const float* __restrict__ bg1,
    const float* __restrict__ bu1, const float* __restrict__ zeta1,
    const float* __restrict__ nu1, float* __restrict__ hrowg,
    float* __restrict__ hcolg) {
  constexpr int ST = 97;
  __shared__ float wxs[112 * ST];  // 43.5 KB

  const int tid = threadIdx.x;
  const int bid = blockIdx.x;
  const bool isrow = bid < 448;
  const int v = isrow ? bid : bid - 448;
  const int b = v / 14, wp = v % 14;
  const int base4 = 8 * wp;
  const int span = (wp == 13) ? 8 : 12;

  // ---- wx phase: per-thread up to 6 pixels; W1 via uniform scalar loads ----
  int qk[6], sk[6];
  const float* pk[6];
  bool actk[6];
#pragma unroll
  for (int k = 0; k < 6; ++k) {
    const int p = tid + 256 * k;
    int q, s;
    if (isrow) { q = p / 12;  s = p - 12 * q; }
    else       { q = p % 112; s = p / 112; }
    qk[k] = q; sk[k] = s;
    actk[k] = (p < 1344) && (s < span);
    pk[k] = isrow
        ? inp + ((size_t)(b * 112 + q) * 112 + base4 + s) * 16
        : inp + ((size_t)(b * 112 + base4 + s) * 112 + q) * 16;
  }

  float acc[6][8];
#pragma unroll
  for (int k = 0; k < 6; ++k)
#pragma unroll
    for (int j = 0; j < 8; ++j) acc[k][j] = 0.f;

#pragma unroll 1
  for (int half = 0; half < 2; ++half) {
    const float* w1h = W1 + half * 64;
#pragma unroll
    for (int k = 0; k < 6; ++k) {
      if (actk[k]) {
        const float4* xp = (const float4*)(pk[k] + half * 8);
        float4 x0 = xp[0], x1 = xp[1];
        float xr[8] = {x0.x, x0.y, x0.z, x0.w, x1.x, x1.y, x1.z, x1.w};
#pragma unroll
        for (int ci = 0; ci < 8; ++ci)
#pragma unroll
          for (int j = 0; j < 8; ++j)
            acc[k][j] = fmaf(xr[ci], w1h[ci * 8 + j], acc[k][j]);
      }
    }
  }

#pragma unroll
  for (int k = 0; k < 6; ++k)
    if (actk[k]) {
      float* wd = &wxs[qk[k] * ST + sk[k] * 8];
#pragma unroll
      for (int j = 0; j < 8; ++j) wd[j] = acc[k][j];
    }

  // ---- uniform recurrence weights (scalar loads -> SGPRs) ----
  float u1r[8][8];
#pragma unroll
  for (int i = 0; i < 8; ++i)
#pragma unroll
    for (int j = 0; j < 8; ++j) u1r[i][j] = U1[i * 8 + j];
  float bgv[8], Kc[8];
#pragma unroll
  for (int j = 0; j < 8; ++j) {
    bgv[j] = bg1[j];
    Kc[j] = __expf(2.f * (bg1[j] - bu1[j]));
  }
  const float zg = frcp(1.f + __expf(-zeta1[0]));
  const float ng = frcp(1.f + __expf(-nu1[0]));
  const float A = zg + ng;

  __syncthreads();

  // ---- recurrence: lane = (wl, r), fully register-resident ----
  const int nact = (wp == 13) ? 112 : 224;
  if (tid < nact) {
    const int wl = tid / 112, r = tid - 112 * wl;
    const int base = r * ST + wl * 32;
    float h[8];
    {
#pragma unroll
      for (int j = 0; j < 8; ++j) {
        float s = __expf(-(wxs[base + j] + bgv[j]));
        float z = frcp(1.f + s);
        float u = s * s * Kc[j];
        float c = fmaf(2.f, frcp(1.f + u), -1.f);
        float m = fmaf(-zg, z, A);
        h[j] = m * c;
      }
    }
#pragma unroll
    for (int t = 1; t < 8; ++t) {
      float qa[8];
#pragma unroll
      for (int j = 0; j < 8; ++j) {
        float q = u1r[0][j] * h[0];
        q = fmaf(u1r[1][j], h[1], q);
        q = fmaf(u1r[2][j], h[2], q);
        q = fmaf(u1r[3][j], h[3], q);
        q = fmaf(u1r[4][j], h[4], q);
        q = fmaf(u1r[5][j], h[5], q);
        q = fmaf(u1r[6][j], h[6], q);
        q = fmaf(u1r[7][j], h[7], q);
        qa[j] = q;
      }
#pragma unroll
      for (int j = 0; j < 8; ++j) {
        float pre = wxs[base + t * 8 + j] + qa[j];
        float s = __expf(-(pre + bgv[j]));
        float z = frcp(1.f + s);
        float u = s * s * Kc[j];
        float c = fmaf(2.f, frcp(1.f + u), -1.f);
        float m = fmaf(-zg, z, A);
        h[j] = fmaf(z, h[j], m * c);
      }
    }
    float* dst = (isrow ? hrowg : hcolg) +
                 ((size_t)(b * 27 + 2 * wp + wl) * 112 + r) * 8;
    ((float4*)dst)[0] = float4{h[0], h[1], h[2], h[3]};
    ((float4*)dst)[1] = float4{h[4], h[5], h[6], h[7]};
  }
}

// ---------------- Kernel B: level-2, DPP cross-lane, 4 patches/block ----------------
// Wave = 1 patch x 4 branches (16-lane rows). Lane = (g, j): owns h2[j] of branch
// g. U2.h2 via row_ror DPP (VALU) — zero LDS, zero barriers, weights resident.
__global__ __launch_bounds__(256) void l2_kernel(
    const float* __restrict__ hrowg, const float* __restrict__ hcolg,
    const float* __restrict__ W2, const float* __restrict__ U2,
    const float* __restrict__ bg2, const float* __restrict__ bu2,
    const float* __restrict__ zeta2, const float* __restrict__ nu2,
    float* __restrict__ out) {
  const int tid = threadIdx.x, wv = tid >> 6, lane = tid & 63;
  const int g = lane >> 4, j = lane & 15;
  const int n = blockIdx.x * 4 + wv;
  const int pw = n % 27;
  const int q = n / 27;
  const int ph = q % 27, b = q / 27;
  const int rev = g & 1;

  const float* hs = (g < 2)
      ? &hrowg[((size_t)(b * 27 + pw) * 112 + ph * 4) * 8]
      : &hcolg[((size_t)(b * 27 + ph) * 112 + pw * 4) * 8];

  float w2c[8];
#pragma unroll
  for (int d = 0; d < 8; ++d) w2c[d] = W2[d * 16 + j];
  float u2r[16];
#pragma unroll
  for (int k = 0; k < 16; ++k) u2r[k] = U2[((j - k) & 15) * 16 + j];
  const float bgv = bg2[j];
  const float Kc = __expf(2.f * (bg2[j] - bu2[j]));
  const float zg = frcp(1.f + __expf(-zeta2[0]));
  const float ng = frcp(1.f + __expf(-nu2[0]));
  const float A = zg + ng;

  float h2 = 0.f;
#pragma unroll
  for (int t = 0; t < 8; ++t) {
    const int tt = rev ? (7 - t) : t;
    const float4* rp = (const float4*)(hs + tt * 8);
    float4 r0 = rp[0], r1 = rp[1];
    float pa = r0.x * w2c[0], pb = r0.y * w2c[1];
    pa = fmaf(r0.z, w2c[2], pa);
    pb = fmaf(r0.w, w2c[3], pb);
    pa = fmaf(r1.x, w2c[4], pa);
    pb = fmaf(r1.y, w2c[5], pb);
    pa = fmaf(r1.z, w2c[6], pa);
    pb = fmaf(r1.w, w2c[7], pb);
    float pre = pa + pb;
    if (t > 0) {
      float a0 = h2 * u2r[0];
      float a1 = rotr<1>(h2) * u2r[1];
      a0 = fmaf(rotr<2>(h2), u2r[2], a0);
      a1 = fmaf(rotr<3>(h2), u2r[3], a1);
      a0 = fmaf(rotr<4>(h2), u2r[4], a0);
      a1 = fmaf(rotr<5>(h2), u2r[5], a1);
      a0 = fmaf(rotr<6>(h2), u2r[6], a0);
      a1 = fmaf(rotr<7>(h2), u2r[7], a1);
      a0 = fmaf(rotr<8>(h2), u2r[8], a0);
      a1 = fmaf(rotr<9>(h2), u2r[9], a1);
      a0 = fmaf(rotr<10>(h2), u2r[10], a0);
      a1 = fmaf(rotr<11>(h2), u2r[11], a1);
      a0 = fmaf(rotr<12>(h2), u2r[12], a0);
      a1 = fmaf(rotr<13>(h2), u2r[13], a1);
      a0 = fmaf(rotr<14>(h2), u2r[14], a0);
      a1 = fmaf(rotr<15>(h2), u2r[15], a1);
      pre += a0 + a1;
    }
    float s = __expf(-(pre + bgv));
    float z = frcp(1.f + s);
    float u = s * s * Kc;
    float c = fmaf(2.f, frcp(1.f + u), -1.f);
    float m = fmaf(-zg, z, A);
    h2 = fmaf(z, h2, m * c);
  }

  out[(size_t)n * 64 + lane] = h2;
}

extern "C" void kernel_launch(void* const* d_in, const int* in_sizes, int n_in,
                              void* d_out, int out_size, void* d_ws, size_t ws_size,
                              hipStream_t stream) {
  const float* inp   = (const float*)d_in[0];
  const float* W1    = (const float*)d_in[1];
  const float* U1    = (const float*)d_in[2];
  const float* bg1   = (const float*)d_in[3];
  const float* bu1   = (const float*)d_in[4];
  const float* zeta1 = (const float*)d_in[5];
  const float* nu1   = (const float*)d_in[6];
  const float* W2    = (const float*)d_in[7];
  const float* U2    = (const float*)d_in[8];
  const float* bg2   = (const float*)d_in[9];
  const float* bu2   = (const float*)d_in[10];
  const float* zeta2 = (const float*)d_in[11];
  const float* nu2   = (const float*)d_in[12];
  float* out = (float*)d_out;

  const size_t HSZ = (size_t)32 * 27 * 112 * 8;  // floats per h buffer
  float* hrowg = (float*)d_ws;
  float* hcolg = hrowg + HSZ;

  // Kernel A: 2 modes x 32 b x 14 window-pairs = 896 blocks
  l1_kernel<<<dim3(896), dim3(256), 0, stream>>>(
      inp, W1, U1, bg1, bu1, zeta1, nu1, hrowg, hcolg);
  // Kernel B: 23328 patches, 4 per 256-block
  l2_kernel<<<dim3(5832), dim3(256), 0, stream>>>(
      hrowg, hcolg, W2, U2, bg2, bu2, zeta2, nu2, out);
}

// Round 10
// 51.785 us; speedup vs baseline: 1.2976x; 1.2976x over previous
//
#include <hip/hip_runtime.h>

#define PPB 4  // waves per 256-thread block

typedef float v2f __attribute__((ext_vector_type(2)));

__device__ __forceinline__ float frcp(float x) { return __builtin_amdgcn_rcpf(x); }

__device__ __forceinline__ v2f vfma2(v2f a, v2f b, v2f c) {
#if __has_builtin(__builtin_elementwise_fma)
  return __builtin_elementwise_fma(a, b, c);
#else
  v2f d; d.x = fmaf(a.x, b.x, c.x); d.y = fmaf(a.y, b.y, c.y); return d;
#endif
}
__device__ __forceinline__ v2f bc(float x) { v2f p; p.x = x; p.y = x; return p; }

template <int K>
__device__ __forceinline__ float rotr(float x) {
  // row_ror:K -> lane i receives lane (i-K)&15 within its 16-lane row
  return __int_as_float(
      __builtin_amdgcn_mov_dpp(__float_as_int(x), 0x120 + K, 0xf, 0xf, true));
}

// packed FastGRNN gate update (2 independent recurrences per lane) — K1 only
__device__ __forceinline__ v2f gate2(v2f pre, v2f h, v2f bgB, v2f KB, v2f nzgB,
                                     v2f AB, bool first) {
  v2f a = pre + bgB;
  v2f s; s.x = __expf(-a.x); s.y = __expf(-a.y);
  v2f one = bc(1.f);
  v2f zd = s + one;
  v2f z; z.x = frcp(zd.x); z.y = frcp(zd.y);
  v2f u = (s * s) * KB;
  v2f cd = u + one;
  v2f cr; cr.x = frcp(cd.x); cr.y = frcp(cd.y);
  v2f cc = vfma2(cr, bc(2.f), bc(-1.f));
  v2f m = vfma2(z, nzgB, AB);
  v2f mc = m * cc;
  return first ? mc : vfma2(z, h, mc);
}

// ---------------- Kernel A: dedup'd level-1, 2 tiles (packed) per wave ----------------
// (bit-identical to round 6's l1_kernel — the best-measured K1)
__global__ __launch_bounds__(256) void l1_kernel(
    const float* __restrict__ inp, const float* __restrict__ W1,
    const float* __restrict__ U1, const float* __restrict__ bg1,
    const float* __restrict__ bu1, const float* __restrict__ zeta1,
    const float* __restrict__ nu1, float* __restrict__ hrowg,
    float* __restrict__ hcolg) {
  constexpr int NP = 6048;   // 32 * 7 * 27 pair-waves per mode
  constexpr int SAs = 68;    // wx scalar a-row stride (floats)
  constexpr int SH = 18;     // hp seq stride (v2 units)

  __shared__ float w1s[128];
  __shared__ float wxs[PPB][16 * SAs];
  __shared__ v2f hp[PPB][7 * SH + 8];

  const int tid = threadIdx.x, wv = tid >> 6, lane = tid & 63;
  const int widx = blockIdx.x * PPB + wv;

  if (tid < 32) ((float4*)w1s)[tid] = ((const float4*)W1)[tid];
  __syncthreads();

  const bool isrow = widx < NP;
  const int v = isrow ? widx : widx - NP;
  const int b = v / 189;        // 7*27
  const int rem = v % 189;
  const int k = rem / 27;       // tile-pair index (0..6)
  const int t27 = rem % 27;     // window index

  const int rr = lane >> 3, cc = lane & 7;
  const int ay = isrow ? (k * 16 + rr) : (t27 * 4 + rr);
  const int ax = isrow ? (t27 * 4 + cc) : (k * 16 + cc);
  const int by = isrow ? (ay + 8) : ay;
  const int bx = isrow ? ax : (ax + 8);

  // ---- wx for both pixels (v2f across j-pairs, weights shared) ----
  {
    const float* pA = inp + ((size_t)(b * 112 + ay) * 112 + ax) * 16;
    const float* pB = inp + ((size_t)(b * 112 + by) * 112 + bx) * 16;
    float4 A0 = ((const float4*)pA)[0], A1 = ((const float4*)pA)[1],
           A2 = ((const float4*)pA)[2], A3 = ((const float4*)pA)[3];
    float4 B0 = ((const float4*)pB)[0], B1 = ((const float4*)pB)[1],
           B2 = ((const float4*)pB)[2], B3 = ((const float4*)pB)[3];
    float xA[16] = {A0.x, A0.y, A0.z, A0.w, A1.x, A1.y, A1.z, A1.w,
                    A2.x, A2.y, A2.z, A2.w, A3.x, A3.y, A3.z, A3.w};
    float xB[16] = {B0.x, B0.y, B0.z, B0.w, B1.x, B1.y, B1.z, B1.w,
                    B2.x, B2.y, B2.z, B2.w, B3.x, B3.y, B3.z, B3.w};
    v2f aA0 = bc(0.f), aA1 = bc(0.f), aA2 = bc(0.f), aA3 = bc(0.f);
    v2f aB0 = bc(0.f), aB1 = bc(0.f), aB2 = bc(0.f), aB3 = bc(0.f);
#pragma unroll
    for (int ci = 0; ci < 16; ++ci) {
      const v2f* wr = (const v2f*)&w1s[ci * 8];
      v2f w0 = wr[0], w1 = wr[1], w2 = wr[2], w3 = wr[3];
      v2f xa = bc(xA[ci]), xb = bc(xB[ci]);
      aA0 = vfma2(xa, w0, aA0); aA1 = vfma2(xa, w1, aA1);
      aA2 = vfma2(xa, w2, aA2); aA3 = vfma2(xa, w3, aA3);
      aB0 = vfma2(xb, w0, aB0); aB1 = vfma2(xb, w1, aB1);
      aB2 = vfma2(xb, w2, aB2); aB3 = vfma2(xb, w3, aB3);
    }
    const int a0 = isrow ? rr : cc;
    const int b0 = isrow ? cc : rr;
    float* wdA = &wxs[wv][a0 * SAs + b0 * 8];
    float* wdB = &wxs[wv][(a0 + 8) * SAs + b0 * 8];
    ((float4*)wdA)[0] = float4{aA0.x, aA0.y, aA1.x, aA1.y};
    ((float4*)wdA)[1] = float4{aA2.x, aA2.y, aA3.x, aA3.y};
    ((float4*)wdB)[0] = float4{aB0.x, aB0.y, aB1.x, aB1.y};
    ((float4*)wdB)[1] = float4{aB2.x, aB2.y, aB3.x, aB3.y};
  }
  __builtin_amdgcn_wave_barrier();

  // ---- packed recurrence: seq = rr, hid = cc; v2 = (tile0, tile1) ----
  const int seq = rr, hid = cc;
  v2f u1b[8];
#pragma unroll
  for (int i = 0; i < 8; ++i) u1b[i] = bc(U1[i * 8 + hid]);
  const float bg1v = bg1[hid], bu1v = bu1[hid];
  const float zg1 = frcp(1.f + __expf(-zeta1[0]));
  const float ng1 = frcp(1.f + __expf(-nu1[0]));
  const v2f bgB = bc(bg1v);
  const v2f KB = bc(__expf(2.f * (bg1v - bu1v)));
  const v2f nzgB = bc(-zg1);
  const v2f AB = bc(zg1 + ng1);

  v2f* hq = &hp[wv][0];
  v2f h = bc(0.f);
  {  // t = 0
    v2f pre;
    pre.x = wxs[wv][seq * SAs + hid];
    pre.y = wxs[wv][(seq + 8) * SAs + hid];
    h = gate2(pre, h, bgB, KB, nzgB, AB, true);
    hq[seq * SH + hid] = h;
  }
  __builtin_amdgcn_wave_barrier();
#pragma unroll
  for (int t = 1; t < 8; ++t) {
    const float4* hr4 = (const float4*)&hq[seq * SH];
    float4 f0 = hr4[0], f1 = hr4[1], f2 = hr4[2], f3 = hr4[3];
    v2f q = v2f{f0.x, f0.y} * u1b[0];
    q = vfma2(v2f{f0.z, f0.w}, u1b[1], q);
    q = vfma2(v2f{f1.x, f1.y}, u1b[2], q);
    q = vfma2(v2f{f1.z, f1.w}, u1b[3], q);
    q = vfma2(v2f{f2.x, f2.y}, u1b[4], q);
    q = vfma2(v2f{f2.z, f2.w}, u1b[5], q);
    q = vfma2(v2f{f3.x, f3.y}, u1b[6], q);
    q = vfma2(v2f{f3.z, f3.w}, u1b[7], q);
    v2f pre;
    pre.x = wxs[wv][seq * SAs + t * 8 + hid];
    pre.y = wxs[wv][(seq + 8) * SAs + t * 8 + hid];
    pre = pre + q;
    h = gate2(pre, h, bgB, KB, nzgB, AB, false);
    hq[seq * SH + hid] = h;
    __builtin_amdgcn_wave_barrier();
  }

  const size_t obase = (((size_t)(b * 27 + t27) * 112) + k * 16 + seq) * 8 + hid;
  float* dst = isrow ? hrowg : hcolg;
  dst[obase] = h.x;
  dst[obase + 64] = h.y;
}

// ---------------- Kernel B: level-2, DPP cross-lane (bit-identical to round 9) ----------------
__global__ __launch_bounds__(256) void l2_kernel(
    const float* __restrict__ hrowg, const float* __restrict__ hcolg,
    const float* __restrict__ W2, const float* __restrict__ U2,
    const float* __restrict__ bg2, const float* __restrict__ bu2,
    const float* __restrict__ zeta2, const float* __restrict__ nu2,
    float* __restrict__ out) {
  const int tid = threadIdx.x, wv = tid >> 6, lane = tid & 63;
  const int g = lane >> 4, j = lane & 15;
  const int n = blockIdx.x * 4 + wv;
  const int pw = n % 27;
  const int q = n / 27;
  const int ph = q % 27, b = q / 27;
  const int rev = g & 1;

  const float* hs = (g < 2)
      ? &hrowg[((size_t)(b * 27 + pw) * 112 + ph * 4) * 8]
      : &hcolg[((size_t)(b * 27 + ph) * 112 + pw * 4) * 8];

  float w2c[8];
#pragma unroll
  for (int d = 0; d < 8; ++d) w2c[d] = W2[d * 16 + j];
  float u2r[16];
#pragma unroll
  for (int k = 0; k < 16; ++k) u2r[k] = U2[((j - k) & 15) * 16 + j];
  const float bgv = bg2[j];
  const float Kc = __expf(2.f * (bg2[j] - bu2[j]));
  const float zg = frcp(1.f + __expf(-zeta2[0]));
  const float ng = frcp(1.f + __expf(-nu2[0]));
  const float A = zg + ng;

  float h2 = 0.f;
#pragma unroll
  for (int t = 0; t < 8; ++t) {
    const int tt = rev ? (7 - t) : t;
    const float4* rp = (const float4*)(hs + tt * 8);
    float4 r0 = rp[0], r1 = rp[1];
    float pa = r0.x * w2c[0], pb = r0.y * w2c[1];
    pa = fmaf(r0.z, w2c[2], pa);
    pb = fmaf(r0.w, w2c[3], pb);
    pa = fmaf(r1.x, w2c[4], pa);
    pb = fmaf(r1.y, w2c[5], pb);
    pa = fmaf(r1.z, w2c[6], pa);
    pb = fmaf(r1.w, w2c[7], pb);
    float pre = pa + pb;
    if (t > 0) {
      float a0 = h2 * u2r[0];
      float a1 = rotr<1>(h2) * u2r[1];
      a0 = fmaf(rotr<2>(h2), u2r[2], a0);
      a1 = fmaf(rotr<3>(h2), u2r[3], a1);
      a0 = fmaf(rotr<4>(h2), u2r[4], a0);
      a1 = fmaf(rotr<5>(h2), u2r[5], a1);
      a0 = fmaf(rotr<6>(h2), u2r[6], a0);
      a1 = fmaf(rotr<7>(h2), u2r[7], a1);
      a0 = fmaf(rotr<8>(h2), u2r[8], a0);
      a1 = fmaf(rotr<9>(h2), u2r[9], a1);
      a0 = fmaf(rotr<10>(h2), u2r[10], a0);
      a1 = fmaf(rotr<11>(h2), u2r[11], a1);
      a0 = fmaf(rotr<12>(h2), u2r[12], a0);
      a1 = fmaf(rotr<13>(h2), u2r[13], a1);
      a0 = fmaf(rotr<14>(h2), u2r[14], a0);
      a1 = fmaf(rotr<15>(h2), u2r[15], a1);
      pre += a0 + a1;
    }
    float s = __expf(-(pre + bgv));
    float z = frcp(1.f + s);
    float u = s * s * Kc;
    float c = fmaf(2.f, frcp(1.f + u), -1.f);
    float m = fmaf(-zg, z, A);
    h2 = fmaf(z, h2, m * c);
  }

  out[(size_t)n * 64 + lane] = h2;
}

extern "C" void kernel_launch(void* const* d_in, const int* in_sizes, int n_in,
                              void* d_out, int out_size, void* d_ws, size_t ws_size,
                              hipStream_t stream) {
  const float* inp   = (const float*)d_in[0];
  const float* W1    = (const float*)d_in[1];
  const float* U1    = (const float*)d_in[2];
  const float* bg1   = (const float*)d_in[3];
  const float* bu1   = (const float*)d_in[4];
  const float* zeta1 = (const float*)d_in[5];
  const float* nu1   = (const float*)d_in[6];
  const float* W2    = (const float*)d_in[7];
  const float* U2    = (const float*)d_in[8];
  const float* bg2   = (const float*)d_in[9];
  const float* bu2   = (const float*)d_in[10];
  const float* zeta2 = (const float*)d_in[11];
  const float* nu2   = (const float*)d_in[12];
  float* out = (float*)d_out;

  const size_t HSZ = (size_t)32 * 27 * 112 * 8;  // floats per h buffer
  float* hrowg = (float*)d_ws;
  float* hcolg = hrowg + HSZ;

  // Kernel A (round-6 variant): 12096 pair-waves, 4/block
  l1_kernel<<<dim3(3024), dim3(256), 0, stream>>>(
      inp, W1, U1, bg1, bu1, zeta1, nu1, hrowg, hcolg);
  // Kernel B (round-9 DPP variant): 23328 patches, 4 per 256-block
  l2_kernel<<<dim3(5832), dim3(256), 0, stream>>>(
      hrowg, hcolg, W2, U2, bg2, bu2, zeta2, nu2, out);
}

// Round 11
// 49.143 us; speedup vs baseline: 1.3673x; 1.0538x over previous
//
#include <hip/hip_runtime.h>

#define PPB 4  // waves per 256-thread block

typedef float v2f __attribute__((ext_vector_type(2)));

__device__ __forceinline__ float frcp(float x) { return __builtin_amdgcn_rcpf(x); }

__device__ __forceinline__ v2f vfma2(v2f a, v2f b, v2f c) {
#if __has_builtin(__builtin_elementwise_fma)
  return __builtin_elementwise_fma(a, b, c);
#else
  v2f d; d.x = fmaf(a.x, b.x, c.x); d.y = fmaf(a.y, b.y, c.y); return d;
#endif
}
__device__ __forceinline__ v2f bc(float x) { v2f p; p.x = x; p.y = x; return p; }

// packed FastGRNN gate update (2 independent recurrences per lane)
__device__ __forceinline__ v2f gate2(v2f pre, v2f h, v2f bgB, v2f KB, v2f nzgB,
                                     v2f AB, bool first) {
  v2f a = pre + bgB;
  v2f s; s.x = __expf(-a.x); s.y = __expf(-a.y);
  v2f one = bc(1.f);
  v2f zd = s + one;
  v2f z; z.x = frcp(zd.x); z.y = frcp(zd.y);
  v2f u = (s * s) * KB;
  v2f cd = u + one;
  v2f cr; cr.x = frcp(cd.x); cr.y = frcp(cd.y);
  v2f cc = vfma2(cr, bc(2.f), bc(-1.f));
  v2f m = vfma2(z, nzgB, AB);
  v2f mc = m * cc;
  return first ? mc : vfma2(z, h, mc);
}

// ---------------- Kernel 0: wx = x . W1 once per pixel, dual layout ----------------
// Lane = (p,j): 8 pixels x 8 outputs per wave-iter. W1 column j in VGPRs.
// wxr[b][y][x][8] coalesced; wxc[b][x][y][8] transposed (32B-chunk scatter).
__global__ __launch_bounds__(256) void wx_kernel(
    const float* __restrict__ inp, const float* __restrict__ W1,
    float* __restrict__ wxr, float* __restrict__ wxc) {
  const int tid = threadIdx.x, wv = tid >> 6, lane = tid & 63;
  const int p = lane >> 3, j = lane & 7;
  const int gw = blockIdx.x * 4 + wv;  // 3136 waves

  float w1c[16];
#pragma unroll
  for (int ci = 0; ci < 16; ++ci) w1c[ci] = W1[ci * 8 + j];

#pragma unroll 1
  for (int it = 0; it < 16; ++it) {
    const int pixel = (gw * 16 + it) * 8 + p;  // < 401408
    const float* src = inp + (size_t)pixel * 16;
    float4 x0 = ((const float4*)src)[0], x1 = ((const float4*)src)[1],
           x2 = ((const float4*)src)[2], x3 = ((const float4*)src)[3];
    float a = x0.x * w1c[0];
    a = fmaf(x0.y, w1c[1], a);
    a = fmaf(x0.z, w1c[2], a);
    a = fmaf(x0.w, w1c[3], a);
    a = fmaf(x1.x, w1c[4], a);
    a = fmaf(x1.y, w1c[5], a);
    a = fmaf(x1.z, w1c[6], a);
    a = fmaf(x1.w, w1c[7], a);
    a = fmaf(x2.x, w1c[8], a);
    a = fmaf(x2.y, w1c[9], a);
    a = fmaf(x2.z, w1c[10], a);
    a = fmaf(x2.w, w1c[11], a);
    a = fmaf(x3.x, w1c[12], a);
    a = fmaf(x3.y, w1c[13], a);
    a = fmaf(x3.z, w1c[14], a);
    a = fmaf(x3.w, w1c[15], a);
    wxr[(size_t)pixel * 8 + j] = a;
    const int b = pixel / 12544;
    const int rem = pixel - b * 12544;
    const int y = rem / 112, x = rem - y * 112;
    wxc[((size_t)(b * 112 + x) * 112 + y) * 8 + j] = a;
  }
}

// ---------------- Kernel A: dedup'd level-1 recurrences (wx from global) ----------------
// R6 structure minus the wx phase: 2 tiles packed per wave, h-sharing in LDS.
__global__ __launch_bounds__(256) void l1_kernel(
    const float* __restrict__ wxr, const float* __restrict__ wxc,
    const float* __restrict__ U1, const float* __restrict__ bg1,
    const float* __restrict__ bu1, const float* __restrict__ zeta1,
    const float* __restrict__ nu1, float* __restrict__ hrowg,
    float* __restrict__ hcolg) {
  constexpr int NP = 6048;  // 32 * 7 * 27 pair-waves per mode
  constexpr int SH = 18;    // hp seq stride (v2 units)

  __shared__ v2f hp[PPB][7 * SH + 8];

  const int tid = threadIdx.x, wv = tid >> 6, lane = tid & 63;
  const int widx = blockIdx.x * PPB + wv;

  const bool isrow = widx < NP;
  const int v = isrow ? widx : widx - NP;
  const int b = v / 189;     // 7*27
  const int rem = v % 189;
  const int k = rem / 27;    // tile-pair index (0..6)
  const int t27 = rem % 27;  // window index

  const int seq = lane >> 3, hid = lane & 7;

  // wx addresses: ((b*112 + q)*112 + t27*4 + t)*8 + hid, q = k*16+seq (+8 tile1)
  const float* wxbase = isrow ? wxr : wxc;
  const size_t base0 = ((size_t)(b * 112 + k * 16 + seq) * 112 + t27 * 4) * 8 + hid;
  const size_t base1 = base0 + (size_t)8 * 112 * 8;

  v2f u1b[8];
#pragma unroll
  for (int i = 0; i < 8; ++i) u1b[i] = bc(U1[i * 8 + hid]);
  const float bg1v = bg1[hid], bu1v = bu1[hid];
  const float zg1 = frcp(1.f + __expf(-zeta1[0]));
  const float ng1 = frcp(1.f + __expf(-nu1[0]));
  const v2f bgB = bc(bg1v);
  const v2f KB = bc(__expf(2.f * (bg1v - bu1v)));
  const v2f nzgB = bc(-zg1);
  const v2f AB = bc(zg1 + ng1);

  v2f* hq = &hp[wv][0];
  v2f h = bc(0.f);
  {  // t = 0
    v2f pre;
    pre.x = wxbase[base0];
    pre.y = wxbase[base1];
    h = gate2(pre, h, bgB, KB, nzgB, AB, true);
    hq[seq * SH + hid] = h;
  }
  __builtin_amdgcn_wave_barrier();
#pragma unroll
  for (int t = 1; t < 8; ++t) {
    const float4* hr4 = (const float4*)&hq[seq * SH];
    float4 f0 = hr4[0], f1 = hr4[1], f2 = hr4[2], f3 = hr4[3];
    v2f q = v2f{f0.x, f0.y} * u1b[0];
    q = vfma2(v2f{f0.z, f0.w}, u1b[1], q);
    q = vfma2(v2f{f1.x, f1.y}, u1b[2], q);
    q = vfma2(v2f{f1.z, f1.w}, u1b[3], q);
    q = vfma2(v2f{f2.x, f2.y}, u1b[4], q);
    q = vfma2(v2f{f2.z, f2.w}, u1b[5], q);
    q = vfma2(v2f{f3.x, f3.y}, u1b[6], q);
    q = vfma2(v2f{f3.z, f3.w}, u1b[7], q);
    v2f pre;
    pre.x = wxbase[base0 + t * 8];
    pre.y = wxbase[base1 + t * 8];
    pre = pre + q;
    h = gate2(pre, h, bgB, KB, nzgB, AB, false);
    hq[seq * SH + hid] = h;
    __builtin_amdgcn_wave_barrier();
  }

  // out: [b][t27][q][hid]; tile0 at k*16+seq, tile1 +8 (= +64 floats)
  const size_t obase = (((size_t)(b * 27 + t27) * 112) + k * 16 + seq) * 8 + hid;
  float* dst = isrow ? hrowg : hcolg;
  dst[obase] = h.x;
  dst[obase + 64] = h.y;
}

// ---------------- Kernel B: level-2, 2 patches (packed) per wave (R6 verbatim) ----------------
__global__ __launch_bounds__(256) void l2_kernel(
    const float* __restrict__ hrowg, const float* __restrict__ hcolg,
    const float* __restrict__ W2, const float* __restrict__ U2,
    const float* __restrict__ bg2, const float* __restrict__ bu2,
    const float* __restrict__ zeta2, const float* __restrict__ nu2,
    float* __restrict__ out) {
  constexpr int GST = 18;  // h2 branch stride (v2 units)
  constexpr int WHT = 18;  // wh row stride (v2 units)
  __shared__ v2f hbI[PPB][128];
  __shared__ v2f whb[PPB][2 * 8 * WHT];
  __shared__ v2f h2I[PPB][3 * GST + 16];

  const int tid = threadIdx.x, wv = tid >> 6, lane = tid & 63;
  const int w = blockIdx.x * PPB + wv;
  const int n0 = 2 * w, n1 = n0 + 1;

  {
    const int p = lane >> 5, half = (lane >> 4) & 1, idx = lane & 15;
    const int pn = p ? n1 : n0;
    const int pw = pn % 27;
    const int qq = pn / 27;
    const int ph = qq % 27, bb = qq / 27;
    const float* src = half ? &hcolg[(((size_t)(bb * 27 + ph)) * 112 + pw * 4) * 8]
                            : &hrowg[(((size_t)(bb * 27 + pw)) * 112 + ph * 4) * 8];
    float4 val = ((const float4*)src)[idx];
    float* base = (float*)&hbI[wv][half * 64 + idx * 4];
    base[0 + p] = val.x;
    base[2 + p] = val.y;
    base[4 + p] = val.z;
    base[6 + p] = val.w;
  }
  __builtin_amdgcn_wave_barrier();

  const int g = lane >> 4, j = lane & 15;
  v2f w2b[8], u2b[16];
#pragma unroll
  for (int d = 0; d < 8; ++d) w2b[d] = bc(W2[d * 16 + j]);
#pragma unroll
  for (int i = 0; i < 16; ++i) u2b[i] = bc(U2[i * 16 + j]);
  const float bg2v = bg2[j], bu2v = bu2[j];
  const float zg2 = frcp(1.f + __expf(-zeta2[0]));
  const float ng2 = frcp(1.f + __expf(-nu2[0]));
  const v2f bgB = bc(bg2v);
  const v2f KB = bc(__expf(2.f * (bg2v - bu2v)));
  const v2f nzgB = bc(-zg2);
  const v2f AB = bc(zg2 + ng2);

  const int src = g >> 1;

  {
    const v2f* hb = &hbI[wv][src * 64];
    const int t0 = (g & 1) * 4;
#pragma unroll
    for (int i = 0; i < 4; ++i) {
      const int t = t0 + i;
      const v2f* hr = &hb[t * 8];
      v2f p = hr[0] * w2b[0];
#pragma unroll
      for (int d = 1; d < 8; ++d) p = vfma2(hr[d], w2b[d], p);
      whb[wv][(src * 8 + t) * WHT + j] = p;
    }
  }
  __builtin_amdgcn_wave_barrier();

  const v2f* whsrc = &whb[wv][src * 8 * WHT];
  v2f* h2q = &h2I[wv][g * GST];

  v2f h2 = bc(0.f);
  {
    const int tt = (g & 1) ? 7 : 0;
    v2f p = whsrc[tt * WHT + j];
    h2 = gate2(p, h2, bgB, KB, nzgB, AB, true);
    h2q[j] = h2;
  }
  __builtin_amdgcn_wave_barrier();
#pragma unroll
  for (int t = 1; t < 8; ++t) {
    const int tt = (g & 1) ? (7 - t) : t;
    v2f p = whsrc[tt * WHT + j];
    const float4* q4 = (const float4*)h2q;
    float4 v0 = q4[0], v1 = q4[1], v2_ = q4[2], v3 = q4[3];
    float4 v4 = q4[4], v5 = q4[5], v6 = q4[6], v7 = q4[7];
    v2f q = v2f{v0.x, v0.y} * u2b[0];
    q = vfma2(v2f{v0.z, v0.w}, u2b[1], q);
    q = vfma2(v2f{v1.x, v1.y}, u2b[2], q);
    q = vfma2(v2f{v1.z, v1.w}, u2b[3], q);
    q = vfma2(v2f{v2_.x, v2_.y}, u2b[4], q);
    q = vfma2(v2f{v2_.z, v2_.w}, u2b[5], q);
    q = vfma2(v2f{v3.x, v3.y}, u2b[6], q);
    q = vfma2(v2f{v3.z, v3.w}, u2b[7], q);
    q = vfma2(v2f{v4.x, v4.y}, u2b[8], q);
    q = vfma2(v2f{v4.z, v4.w}, u2b[9], q);
    q = vfma2(v2f{v5.x, v5.y}, u2b[10], q);
    q = vfma2(v2f{v5.z, v5.w}, u2b[11], q);
    q = vfma2(v2f{v6.x, v6.y}, u2b[12], q);
    q = vfma2(v2f{v6.z, v6.w}, u2b[13], q);
    q = vfma2(v2f{v7.x, v7.y}, u2b[14], q);
    q = vfma2(v2f{v7.z, v7.w}, u2b[15], q);
    v2f pre = p + q;
    h2 = gate2(pre, h2, bgB, KB, nzgB, AB, false);
    if (t < 7) {
      h2q[j] = h2;
      __builtin_amdgcn_wave_barrier();
    }
  }

  out[(size_t)n0 * 64 + lane] = h2.x;
  out[(size_t)n1 * 64 + lane] = h2.y;
}

extern "C" void kernel_launch(void* const* d_in, const int* in_sizes, int n_in,
                              void* d_out, int out_size, void* d_ws, size_t ws_size,
                              hipStream_t stream) {
  const float* inp   = (const float*)d_in[0];
  const float* W1    = (const float*)d_in[1];
  const float* U1    = (const float*)d_in[2];
  const float* bg1   = (const float*)d_in[3];
  const float* bu1   = (const float*)d_in[4];
  const float* zeta1 = (const float*)d_in[5];
  const float* nu1   = (const float*)d_in[6];
  const float* W2    = (const float*)d_in[7];
  const float* U2    = (const float*)d_in[8];
  const float* bg2   = (const float*)d_in[9];
  const float* bu2   = (const float*)d_in[10];
  const float* zeta2 = (const float*)d_in[11];
  const float* nu2   = (const float*)d_in[12];
  float* out = (float*)d_out;

  const size_t WXSZ = (size_t)32 * 112 * 112 * 8;  // 3211264 floats
  const size_t HSZ = (size_t)32 * 27 * 112 * 8;    // 774144 floats
  float* wxr = (float*)d_ws;
  float* wxc = wxr + WXSZ;
  float* hrowg = wxc + WXSZ;
  float* hcolg = hrowg + HSZ;

  // K0: 401408 pixels, 8/wave-iter, 16 iters/wave, 4 waves/block -> 784 blocks
  wx_kernel<<<dim3(784), dim3(256), 0, stream>>>(inp, W1, wxr, wxc);
  // K1: 12096 pair-waves (row+col), 4/block
  l1_kernel<<<dim3(3024), dim3(256), 0, stream>>>(
      wxr, wxc, U1, bg1, bu1, zeta1, nu1, hrowg, hcolg);
  // K2: 11664 patch-pair waves, 4/block
  l2_kernel<<<dim3(2916), dim3(256), 0, stream>>>(
      hrowg, hcolg, W2, U2, bg2, bu2, zeta2, nu2, out);
}